// Round 4
// baseline (415.270 us; speedup 1.0000x reference)
//
#include <hip/hip_runtime.h>
#include <math.h>

#define EPSV 1e-6f

namespace {

constexpr int FIN   = 16;
constexpr int FOUT  = 32;
constexpr int SLOTS = 8;
constexpr int EPT   = 2;                 // batch elements per thread
constexpr int ELEMS = SLOTS * EPT;       // 16 batch elements per block-iteration
constexpr int BLK   = 32 * SLOTS;        // 256 threads
constexpr int GRID  = 1024;              // 4 blocks/CU * 256 CUs -> zero tail

// Cl(3,0), blade order: 1, e1, e2, e3, e12, e13, e23, e123 (masks 0,1,2,4,3,5,6,7).
// GJ[i][k] = output blade index for the einsum term with h-blade i, xr-blade k
//            (output mask = mask_i ^ mask_k).
constexpr int GJ[8][8] = {
  {0,1,2,3,4,5,6,7},
  {1,0,4,5,2,3,7,6},
  {2,4,0,6,1,7,3,5},
  {3,5,6,0,7,1,2,4},
  {4,2,1,7,0,6,5,3},
  {5,3,7,1,6,0,4,2},
  {6,7,3,2,5,4,0,1},
  {7,6,5,4,3,2,1,0},
};
// Sign for einsum 'bci,cijk,bck->bcj' with cayley[left, right, result]:
// xr contracts the RESULT axis, output is the RIGHT-OPERAND axis, so the
// sign is sgn(mask_i, mask_out) = sgn(mask_i, mask_i^mask_k) — the plain-GP
// sign table with rows of grade-2/3 i (rows 4..7) negated (reversion).
constexpr float SREF[8][8] = {
  { 1, 1, 1, 1, 1, 1, 1, 1},
  { 1, 1, 1, 1, 1, 1, 1, 1},
  { 1,-1, 1, 1,-1,-1, 1,-1},
  { 1,-1,-1, 1, 1,-1,-1, 1},
  {-1, 1,-1,-1, 1, 1,-1, 1},
  {-1, 1, 1,-1,-1, 1, 1,-1},
  {-1,-1, 1,-1, 1,-1, 1, 1},
  {-1,-1, 1,-1, 1,-1, 1, 1},
};
// Only 20 distinct (g_i, g_out, g_k) triples occur; GSLOT maps (i,k) -> slot in
// a 20-entry per-thread register cache of gp_w[c]; SLOT_OFF maps slot -> flat
// offset g_i*16 + g_out*4 + g_k inside gp_w[c][4][4][4].
constexpr int GSLOT[8][8] = {
  {0,1,1,1,2,2,2,3},
  {5,4,7,7,6,6,9,8},
  {5,7,4,7,6,9,6,8},
  {5,7,7,4,9,6,6,8},
  {13,11,11,15,10,14,14,12},
  {13,11,15,11,14,10,14,12},
  {13,15,11,11,14,14,10,12},
  {19,18,18,18,17,17,17,16},
};
constexpr int SLOT_OFF[20] = {0,5,10,15,17,20,22,25,27,30,34,37,39,40,42,45,51,54,57,60};

} // namespace

__global__ __launch_bounds__(BLK, 4)
void cge_block_kernel(const float* __restrict__ x,
                      const float* __restrict__ w1,
                      const float* __restrict__ b1,
                      const float* __restrict__ a_relu,
                      const float* __restrict__ b_relu,
                      const float* __restrict__ wl,
                      const float* __restrict__ bl,
                      const float* __restrict__ wr,
                      const float* __restrict__ a_norm,
                      const float* __restrict__ gp_w,
                      const float* __restrict__ a_ln,
                      float* __restrict__ out,
                      int B)
{
  // wr transposed to [m][c] in LDS so 32 c-lanes read 32 contiguous 16B chunks.
  // w1 and wl stay in global (8 KB / 16 KB L1-hot per-channel rows): 40 KB LDS
  // -> 4 blocks/CU (up from 48 KB / 3), grid 1024 = exactly 4*256, zero tail.
  __shared__ float4 wrs[FOUT * FOUT];    // 16 KB
  __shared__ float4 xs[2][ELEMS * FIN];  // 8 KB   [lo/hi blades][e][m]
  __shared__ float4 hs[2][ELEMS * FOUT]; // 16 KB  [lo/hi blades][e][c]

  const int tid  = threadIdx.x;
  const int c    = tid & 31;
  const int slot = tid >> 5;

  // ---- stage wr to LDS (transpose c-major -> m-major) ----
  for (int idx = tid; idx < FOUT * FOUT; idx += BLK) {
    int cc = idx >> 5, m = idx & 31;
    wrs[m * FOUT + cc] = ((const float4*)wr)[idx];
  }

  // ---- per-thread (channel c) constants in registers ----
  float gw[20];
#pragma unroll
  for (int s = 0; s < 20; ++s) gw[s] = gp_w[c * 64 + SLOT_OFF[s]];
  const float  b1c  = b1[c];
  const float  blc  = bl[c];
  const float  alnc = a_ln[c];
  const float4 ar   = ((const float4*)a_relu)[c];
  const float4 br   = ((const float4*)b_relu)[c];
  const float4 an   = ((const float4*)a_norm)[c];
  const float  sg0  = 1.f / (1.f + expf(-an.x));
  const float  sg1  = 1.f / (1.f + expf(-an.y));
  const float  sg2  = 1.f / (1.f + expf(-an.z));
  const float  sg3  = 1.f / (1.f + expf(-an.w));
  const float4* wlc = ((const float4*)wl) + c * FOUT;  // wl[c][m], L1-resident
  const float4* w1c = ((const float4*)w1) + c * FIN;   // w1[c][m], L1-resident

  const int ngroups = B / ELEMS;

  for (int g = blockIdx.x; g < ngroups; g += gridDim.x) {
    const int eb = g * ELEMS;
    __syncthreads();  // previous iteration's hs/xs reads done

    // ---- stage x: 16 elements * 32 float4, coalesced ----
    {
      const float4* xg = ((const float4*)x) + (size_t)eb * (FIN * 2);
#pragma unroll
      for (int t = 0; t < (ELEMS * FIN * 2) / BLK; ++t) {
        int idx = tid + t * BLK;
        float4 v = xg[idx];
        int e = idx >> 5, r = idx & 31;
        xs[r & 1][e * FIN + (r >> 1)] = v;
      }
    }
    __syncthreads();

    // ---- phase 1: h = relu-gate(w1 @ x + b1) ----
    float h0[EPT][8];
#pragma unroll
    for (int e = 0; e < EPT; ++e) {
      h0[e][0] = b1c;
#pragma unroll
      for (int i = 1; i < 8; ++i) h0[e][i] = 0.f;
    }
#pragma unroll 4
    for (int m = 0; m < FIN; ++m) {
      const float4 w = w1c[m];  // global, L1-hot (8 KB working set)
#pragma unroll
      for (int e = 0; e < EPT; ++e) {
        const int le = slot * EPT + e;
        const float4 xlo = xs[0][le * FIN + m];
        const float4 xhi = xs[1][le * FIN + m];
        h0[e][0] += xlo.x * w.x;
        h0[e][1] += xlo.y * w.y;
        h0[e][2] += xlo.z * w.y;
        h0[e][3] += xlo.w * w.y;
        h0[e][4] += xhi.x * w.z;
        h0[e][5] += xhi.y * w.z;
        h0[e][6] += xhi.z * w.z;
        h0[e][7] += xhi.w * w.w;
      }
    }
#pragma unroll
    for (int e = 0; e < EPT; ++e) {
      const int le = slot * EPT + e;
      const float q1 = h0[e][1]*h0[e][1] + h0[e][2]*h0[e][2] + h0[e][3]*h0[e][3];
      const float q2 = h0[e][4]*h0[e][4] + h0[e][5]*h0[e][5] + h0[e][6]*h0[e][6];
      const float q3 = h0[e][7]*h0[e][7];
      const float g0 = fmaxf(ar.x * h0[e][0] + br.x, 0.f);  // scalar blade: raw value
      const float g1 = fmaxf(ar.y * q1 + br.y, 0.f);
      const float g2 = fmaxf(ar.z * q2 + br.z, 0.f);
      const float g3 = fmaxf(ar.w * q3 + br.w, 0.f);
      h0[e][0] *= g0;
      h0[e][1] *= g1; h0[e][2] *= g1; h0[e][3] *= g1;
      h0[e][4] *= g2; h0[e][5] *= g2; h0[e][6] *= g2;
      h0[e][7] *= g3;
      hs[0][le * FOUT + c] = make_float4(h0[e][0], h0[e][1], h0[e][2], h0[e][3]);
      hs[1][le * FOUT + c] = make_float4(h0[e][4], h0[e][5], h0[e][6], h0[e][7]);
    }
    __syncthreads();

    // ---- fused phase 2+3: xr = wr @ h  and  hl = wl @ h + bl, one hs pass ----
    float xr[EPT][8], hl[EPT][8];
#pragma unroll
    for (int e = 0; e < EPT; ++e) {
      hl[e][0] = blc;
      xr[e][0] = 0.f;
#pragma unroll
      for (int i = 1; i < 8; ++i) { xr[e][i] = 0.f; hl[e][i] = 0.f; }
    }
#pragma unroll 2
    for (int m = 0; m < FOUT; ++m) {
      const float4 wrv = wrs[m * FOUT + c];
      const float4 wlv = wlc[m];  // global, L1-hot (16 KB working set)
#pragma unroll
      for (int e = 0; e < EPT; ++e) {
        const int le = slot * EPT + e;
        const float4 hlo = hs[0][le * FOUT + m];
        const float4 hhi = hs[1][le * FOUT + m];
        xr[e][0] += hlo.x * wrv.x;  hl[e][0] += hlo.x * wlv.x;
        xr[e][1] += hlo.y * wrv.y;  hl[e][1] += hlo.y * wlv.y;
        xr[e][2] += hlo.z * wrv.y;  hl[e][2] += hlo.z * wlv.y;
        xr[e][3] += hlo.w * wrv.y;  hl[e][3] += hlo.w * wlv.y;
        xr[e][4] += hhi.x * wrv.z;  hl[e][4] += hhi.x * wlv.z;
        xr[e][5] += hhi.y * wrv.z;  hl[e][5] += hhi.y * wlv.z;
        xr[e][6] += hhi.z * wrv.z;  hl[e][6] += hhi.z * wlv.z;
        xr[e][7] += hhi.w * wrv.w;  hl[e][7] += hhi.w * wlv.w;
      }
    }

    // ---- grade-normalize xr ----
#pragma unroll
    for (int e = 0; e < EPT; ++e) {
      const float q0 = xr[e][0]*xr[e][0];
      const float q1 = xr[e][1]*xr[e][1] + xr[e][2]*xr[e][2] + xr[e][3]*xr[e][3];
      const float q2 = xr[e][4]*xr[e][4] + xr[e][5]*xr[e][5] + xr[e][6]*xr[e][6];
      const float q3 = xr[e][7]*xr[e][7];
      const float r0 = 1.f / (sg0 * (sqrtf(q0) - 1.f) + 1.f + EPSV);
      const float r1 = 1.f / (sg1 * (sqrtf(q1) - 1.f) + 1.f + EPSV);
      const float r2 = 1.f / (sg2 * (sqrtf(q2) - 1.f) + 1.f + EPSV);
      const float r3 = 1.f / (sg3 * (sqrtf(q3) - 1.f) + 1.f + EPSV);
      xr[e][0] *= r0;
      xr[e][1] *= r1; xr[e][2] *= r1; xr[e][3] *= r1;
      xr[e][4] *= r2; xr[e][5] *= r2; xr[e][6] *= r2;
      xr[e][7] *= r3;
    }

    // ---- sparse steerable GP: 64 terms, weights from 20-entry register cache ----
#pragma unroll
    for (int i = 0; i < 8; ++i) {
#pragma unroll
      for (int k = 0; k < 8; ++k) {
        const float w = SREF[i][k] * gw[GSLOT[i][k]];  // sign folds to neg-modifier
#pragma unroll
        for (int e = 0; e < EPT; ++e) {
          hl[e][GJ[i][k]] += (w * h0[e][i]) * xr[e][k];
        }
      }
    }

    // ---- phase 4: 1/sqrt(2) scale, MVLayerNorm across channels, store ----
#pragma unroll
    for (int e = 0; e < EPT; ++e) {
      const int le = slot * EPT + e;
      float s = 0.f;
#pragma unroll
      for (int i = 0; i < 8; ++i) {
        hl[e][i] *= 0.70710678118654752f;
        s += hl[e][i] * hl[e][i];
      }
      float n = sqrtf(s);
      n += __shfl_xor(n, 1);
      n += __shfl_xor(n, 2);
      n += __shfl_xor(n, 4);
      n += __shfl_xor(n, 8);
      n += __shfl_xor(n, 16);   // stays inside the 32-lane half-wave
      const float scale = alnc / (n * (1.f / FOUT) + EPSV);
      float4* o4 = (float4*)out + (size_t)(eb + le) * (FOUT * 2) + c * 2;
      o4[0] = make_float4(hl[e][0] * scale, hl[e][1] * scale,
                          hl[e][2] * scale, hl[e][3] * scale);
      o4[1] = make_float4(hl[e][4] * scale, hl[e][5] * scale,
                          hl[e][6] * scale, hl[e][7] * scale);
    }
  }
}

extern "C" void kernel_launch(void* const* d_in, const int* in_sizes, int n_in,
                              void* d_out, int out_size, void* d_ws, size_t ws_size,
                              hipStream_t stream) {
  const float* x      = (const float*)d_in[0];
  const float* w1     = (const float*)d_in[1];
  const float* b1     = (const float*)d_in[2];
  const float* a_relu = (const float*)d_in[3];
  const float* b_relu = (const float*)d_in[4];
  const float* wl     = (const float*)d_in[5];
  const float* bl     = (const float*)d_in[6];
  const float* wr     = (const float*)d_in[7];
  const float* a_norm = (const float*)d_in[8];
  const float* gp_w   = (const float*)d_in[9];
  const float* a_ln   = (const float*)d_in[10];
  // d_in[11] = cayley — fixed for Cl(3,0); tables are baked in.

  const int B = in_sizes[0] / (FIN * 8);       // 131072
  const int ngroups = B / ELEMS;               // B divisible by 16 here
  const int grid = ngroups < GRID ? ngroups : GRID;

  cge_block_kernel<<<grid, BLK, 0, stream>>>(
      x, w1, b1, a_relu, b_relu, wl, bl, wr, a_norm, gp_w, a_ln,
      (float*)d_out, B);
}

// Round 5
// 365.682 us; speedup vs baseline: 1.1356x; 1.1356x over previous
//
#include <hip/hip_runtime.h>
#include <math.h>

#define EPSV 1e-6f

namespace {

constexpr int FIN   = 16;
constexpr int FOUT  = 32;
constexpr int SLOTS = 16;                // 16 slots * 32 channels = 512 threads
constexpr int EPT   = 2;                 // batch elements per thread
constexpr int ELEMS = SLOTS * EPT;       // 32 batch elements per block-iteration
constexpr int BLK   = 32 * SLOTS;        // 512 threads = 8 waves
constexpr int GRID  = 512;               // 2 blocks/CU * 256 CUs -> zero tail

// Cl(3,0), blade order: 1, e1, e2, e3, e12, e13, e23, e123 (masks 0,1,2,4,3,5,6,7).
// GJ[i][k] = output blade index for the einsum term with h-blade i, xr-blade k
//            (output mask = mask_i ^ mask_k).
constexpr int GJ[8][8] = {
  {0,1,2,3,4,5,6,7},
  {1,0,4,5,2,3,7,6},
  {2,4,0,6,1,7,3,5},
  {3,5,6,0,7,1,2,4},
  {4,2,1,7,0,6,5,3},
  {5,3,7,1,6,0,4,2},
  {6,7,3,2,5,4,0,1},
  {7,6,5,4,3,2,1,0},
};
// Sign for einsum 'bci,cijk,bck->bcj' with cayley[left, right, result]:
// xr contracts the RESULT axis, output is the RIGHT-OPERAND axis, so the
// sign is sgn(mask_i, mask_out) = sgn(mask_i, mask_i^mask_k) — the plain-GP
// sign table with rows of grade-2/3 i (rows 4..7) negated (reversion).
constexpr float SREF[8][8] = {
  { 1, 1, 1, 1, 1, 1, 1, 1},
  { 1, 1, 1, 1, 1, 1, 1, 1},
  { 1,-1, 1, 1,-1,-1, 1,-1},
  { 1,-1,-1, 1, 1,-1,-1, 1},
  {-1, 1,-1,-1, 1, 1,-1, 1},
  {-1, 1, 1,-1,-1, 1, 1,-1},
  {-1,-1, 1,-1, 1,-1, 1, 1},
  {-1,-1, 1,-1, 1,-1, 1, 1},
};
// Only 20 distinct (g_i, g_out, g_k) triples occur; GSLOT maps (i,k) -> slot in
// a 20-entry per-thread register cache of gp_w[c]; SLOT_OFF maps slot -> flat
// offset g_i*16 + g_out*4 + g_k inside gp_w[c][4][4][4].
constexpr int GSLOT[8][8] = {
  {0,1,1,1,2,2,2,3},
  {5,4,7,7,6,6,9,8},
  {5,7,4,7,6,9,6,8},
  {5,7,7,4,9,6,6,8},
  {13,11,11,15,10,14,14,12},
  {13,11,15,11,14,10,14,12},
  {13,15,11,11,14,14,10,12},
  {19,18,18,18,17,17,17,16},
};
constexpr int SLOT_OFF[20] = {0,5,10,15,17,20,22,25,27,30,34,37,39,40,42,45,51,54,57,60};

} // namespace

__global__ __launch_bounds__(BLK, 4)
void cge_block_kernel(const float* __restrict__ x,
                      const float* __restrict__ w1,
                      const float* __restrict__ b1,
                      const float* __restrict__ a_relu,
                      const float* __restrict__ b_relu,
                      const float* __restrict__ wl,
                      const float* __restrict__ bl,
                      const float* __restrict__ wr,
                      const float* __restrict__ a_norm,
                      const float* __restrict__ gp_w,
                      const float* __restrict__ a_ln,
                      float* __restrict__ out,
                      int B)
{
  // weights transposed to [m][c] so 32 c-lanes read 32 contiguous 16B chunks.
  // 512-thread block: one copy of staged weights serves 32 elements.
  // LDS = 8+16+16+32 = 72 KB -> 2 blocks/CU = 16 waves/CU (4/SIMD), with
  // FEWER blocks than before (512) — tests waves-vs-blocks for latency hiding
  // without the 4-block L3-thrash regression seen in R2/R4.
  __shared__ float4 w1s[FIN * FOUT];     // 8 KB
  __shared__ float4 wrs[FOUT * FOUT];    // 16 KB
  __shared__ float4 xs[2][ELEMS * FIN];  // 16 KB  [lo/hi blades][e][m]
  __shared__ float4 hs[2][ELEMS * FOUT]; // 32 KB  [lo/hi blades][e][c]

  const int tid  = threadIdx.x;
  const int c    = tid & 31;
  const int slot = tid >> 5;

  // ---- stage weights to LDS (transpose c-major -> m-major) ----
  for (int idx = tid; idx < FIN * FOUT; idx += BLK) {
    int cc = idx >> 4, m = idx & 15;
    w1s[m * FOUT + cc] = ((const float4*)w1)[idx];
  }
  for (int idx = tid; idx < FOUT * FOUT; idx += BLK) {
    int cc = idx >> 5, m = idx & 31;
    wrs[m * FOUT + cc] = ((const float4*)wr)[idx];
  }

  // ---- per-thread (channel c) constants in registers ----
  float gw[20];
#pragma unroll
  for (int s = 0; s < 20; ++s) gw[s] = gp_w[c * 64 + SLOT_OFF[s]];
  const float  b1c  = b1[c];
  const float  blc  = bl[c];
  const float  alnc = a_ln[c];
  const float4 ar   = ((const float4*)a_relu)[c];
  const float4 br   = ((const float4*)b_relu)[c];
  const float4 an   = ((const float4*)a_norm)[c];
  const float  sg0  = 1.f / (1.f + expf(-an.x));
  const float  sg1  = 1.f / (1.f + expf(-an.y));
  const float  sg2  = 1.f / (1.f + expf(-an.z));
  const float  sg3  = 1.f / (1.f + expf(-an.w));
  const float4* wlc = ((const float4*)wl) + c * FOUT;  // wl[c][m], L1-resident

  const int ngroups = B / ELEMS;

  for (int g = blockIdx.x; g < ngroups; g += gridDim.x) {
    const int eb = g * ELEMS;
    __syncthreads();  // previous iteration's hs/xs reads done

    // ---- stage x: 32 elements * 32 float4, coalesced ----
    {
      const float4* xg = ((const float4*)x) + (size_t)eb * (FIN * 2);
#pragma unroll
      for (int t = 0; t < (ELEMS * FIN * 2) / BLK; ++t) {
        int idx = tid + t * BLK;
        float4 v = xg[idx];
        int e = idx >> 5, r = idx & 31;
        xs[r & 1][e * FIN + (r >> 1)] = v;
      }
    }
    __syncthreads();

    // ---- phase 1: h = relu-gate(w1 @ x + b1) ----
    float h0[EPT][8];
#pragma unroll
    for (int e = 0; e < EPT; ++e) {
      h0[e][0] = b1c;
#pragma unroll
      for (int i = 1; i < 8; ++i) h0[e][i] = 0.f;
    }
#pragma unroll 4
    for (int m = 0; m < FIN; ++m) {
      const float4 w = w1s[m * FOUT + c];
#pragma unroll
      for (int e = 0; e < EPT; ++e) {
        const int le = slot * EPT + e;
        const float4 xlo = xs[0][le * FIN + m];
        const float4 xhi = xs[1][le * FIN + m];
        h0[e][0] += xlo.x * w.x;
        h0[e][1] += xlo.y * w.y;
        h0[e][2] += xlo.z * w.y;
        h0[e][3] += xlo.w * w.y;
        h0[e][4] += xhi.x * w.z;
        h0[e][5] += xhi.y * w.z;
        h0[e][6] += xhi.z * w.z;
        h0[e][7] += xhi.w * w.w;
      }
    }
#pragma unroll
    for (int e = 0; e < EPT; ++e) {
      const int le = slot * EPT + e;
      const float q1 = h0[e][1]*h0[e][1] + h0[e][2]*h0[e][2] + h0[e][3]*h0[e][3];
      const float q2 = h0[e][4]*h0[e][4] + h0[e][5]*h0[e][5] + h0[e][6]*h0[e][6];
      const float q3 = h0[e][7]*h0[e][7];
      const float g0 = fmaxf(ar.x * h0[e][0] + br.x, 0.f);  // scalar blade: raw value
      const float g1 = fmaxf(ar.y * q1 + br.y, 0.f);
      const float g2 = fmaxf(ar.z * q2 + br.z, 0.f);
      const float g3 = fmaxf(ar.w * q3 + br.w, 0.f);
      h0[e][0] *= g0;
      h0[e][1] *= g1; h0[e][2] *= g1; h0[e][3] *= g1;
      h0[e][4] *= g2; h0[e][5] *= g2; h0[e][6] *= g2;
      h0[e][7] *= g3;
      hs[0][le * FOUT + c] = make_float4(h0[e][0], h0[e][1], h0[e][2], h0[e][3]);
      hs[1][le * FOUT + c] = make_float4(h0[e][4], h0[e][5], h0[e][6], h0[e][7]);
    }
    __syncthreads();

    // ---- fused phase 2+3: xr = wr @ h  and  hl = wl @ h + bl, one hs pass ----
    float xr[EPT][8], hl[EPT][8];
#pragma unroll
    for (int e = 0; e < EPT; ++e) {
      hl[e][0] = blc;
      xr[e][0] = 0.f;
#pragma unroll
      for (int i = 1; i < 8; ++i) { xr[e][i] = 0.f; hl[e][i] = 0.f; }
    }
#pragma unroll 2
    for (int m = 0; m < FOUT; ++m) {
      const float4 wrv = wrs[m * FOUT + c];
      const float4 wlv = wlc[m];  // global, L1-hot (16 KB working set)
#pragma unroll
      for (int e = 0; e < EPT; ++e) {
        const int le = slot * EPT + e;
        const float4 hlo = hs[0][le * FOUT + m];
        const float4 hhi = hs[1][le * FOUT + m];
        xr[e][0] += hlo.x * wrv.x;  hl[e][0] += hlo.x * wlv.x;
        xr[e][1] += hlo.y * wrv.y;  hl[e][1] += hlo.y * wlv.y;
        xr[e][2] += hlo.z * wrv.y;  hl[e][2] += hlo.z * wlv.y;
        xr[e][3] += hlo.w * wrv.y;  hl[e][3] += hlo.w * wlv.y;
        xr[e][4] += hhi.x * wrv.z;  hl[e][4] += hhi.x * wlv.z;
        xr[e][5] += hhi.y * wrv.z;  hl[e][5] += hhi.y * wlv.z;
        xr[e][6] += hhi.z * wrv.z;  hl[e][6] += hhi.z * wlv.z;
        xr[e][7] += hhi.w * wrv.w;  hl[e][7] += hhi.w * wlv.w;
      }
    }

    // ---- grade-normalize xr ----
#pragma unroll
    for (int e = 0; e < EPT; ++e) {
      const float q0 = xr[e][0]*xr[e][0];
      const float q1 = xr[e][1]*xr[e][1] + xr[e][2]*xr[e][2] + xr[e][3]*xr[e][3];
      const float q2 = xr[e][4]*xr[e][4] + xr[e][5]*xr[e][5] + xr[e][6]*xr[e][6];
      const float q3 = xr[e][7]*xr[e][7];
      const float r0 = 1.f / (sg0 * (sqrtf(q0) - 1.f) + 1.f + EPSV);
      const float r1 = 1.f / (sg1 * (sqrtf(q1) - 1.f) + 1.f + EPSV);
      const float r2 = 1.f / (sg2 * (sqrtf(q2) - 1.f) + 1.f + EPSV);
      const float r3 = 1.f / (sg3 * (sqrtf(q3) - 1.f) + 1.f + EPSV);
      xr[e][0] *= r0;
      xr[e][1] *= r1; xr[e][2] *= r1; xr[e][3] *= r1;
      xr[e][4] *= r2; xr[e][5] *= r2; xr[e][6] *= r2;
      xr[e][7] *= r3;
    }

    // ---- sparse steerable GP: 64 terms, weights from 20-entry register cache ----
#pragma unroll
    for (int i = 0; i < 8; ++i) {
#pragma unroll
      for (int k = 0; k < 8; ++k) {
        const float w = SREF[i][k] * gw[GSLOT[i][k]];  // sign folds to neg-modifier
#pragma unroll
        for (int e = 0; e < EPT; ++e) {
          hl[e][GJ[i][k]] += (w * h0[e][i]) * xr[e][k];
        }
      }
    }

    // ---- phase 4: 1/sqrt(2) scale, MVLayerNorm across channels, store ----
#pragma unroll
    for (int e = 0; e < EPT; ++e) {
      const int le = slot * EPT + e;
      float s = 0.f;
#pragma unroll
      for (int i = 0; i < 8; ++i) {
        hl[e][i] *= 0.70710678118654752f;
        s += hl[e][i] * hl[e][i];
      }
      float n = sqrtf(s);
      n += __shfl_xor(n, 1);
      n += __shfl_xor(n, 2);
      n += __shfl_xor(n, 4);
      n += __shfl_xor(n, 8);
      n += __shfl_xor(n, 16);   // stays inside the 32-lane half-wave
      const float scale = alnc / (n * (1.f / FOUT) + EPSV);
      float4* o4 = (float4*)out + (size_t)(eb + le) * (FOUT * 2) + c * 2;
      o4[0] = make_float4(hl[e][0] * scale, hl[e][1] * scale,
                          hl[e][2] * scale, hl[e][3] * scale);
      o4[1] = make_float4(hl[e][4] * scale, hl[e][5] * scale,
                          hl[e][6] * scale, hl[e][7] * scale);
    }
  }
}

extern "C" void kernel_launch(void* const* d_in, const int* in_sizes, int n_in,
                              void* d_out, int out_size, void* d_ws, size_t ws_size,
                              hipStream_t stream) {
  const float* x      = (const float*)d_in[0];
  const float* w1     = (const float*)d_in[1];
  const float* b1     = (const float*)d_in[2];
  const float* a_relu = (const float*)d_in[3];
  const float* b_relu = (const float*)d_in[4];
  const float* wl     = (const float*)d_in[5];
  const float* bl     = (const float*)d_in[6];
  const float* wr     = (const float*)d_in[7];
  const float* a_norm = (const float*)d_in[8];
  const float* gp_w   = (const float*)d_in[9];
  const float* a_ln   = (const float*)d_in[10];
  // d_in[11] = cayley — fixed for Cl(3,0); tables are baked in.

  const int B = in_sizes[0] / (FIN * 8);       // 131072
  const int ngroups = B / ELEMS;               // 4096 here (B divisible by 32)
  const int grid = ngroups < GRID ? ngroups : GRID;

  cge_block_kernel<<<grid, BLK, 0, stream>>>(
      x, w1, b1, a_relu, b_relu, wl, bl, wr, a_norm, gp_w, a_ln,
      (float*)d_out, B);
}